// Round 7
// baseline (231.395 us; speedup 1.0000x reference)
//
#include <hip/hip_runtime.h>
#include <math.h>

typedef float v2f __attribute__((ext_vector_type(2)));

#define B_SEQ 65536
#define T_SEQ 34
#define VOCAB 14
#define SEQS_PER_BLK 64
#define BLK_THREADS 1024                  // 16 waves, all fully active
#define NBLK (B_SEQ / SEQS_PER_BLK)       // 1024, exact
#define NSTATE (T_SEQ * VOCAB)            // 476 distinct (t, token) states
#define ESTRIDE 20                        // floats per table entry (80 B)
#define ENT_B 80
#define SROW_B (VOCAB * ENT_B)            // 1120 B per s-row

__device__ __forceinline__ void layernorm6(const float* x, const float* g,
                                           const float* bt, float* o) {
    float mu = (x[0] + x[1] + x[2] + x[3] + x[4] + x[5]) * (1.0f / 6.0f);
    float var = 0.0f;
#pragma unroll
    for (int i = 0; i < 6; ++i) { float d = x[i] - mu; var += d * d; }
    var *= (1.0f / 6.0f);
    float rs = __builtin_amdgcn_rsqf(var + 1e-5f);
#pragma unroll
    for (int i = 0; i < 6; ++i) o[i] = (x[i] - mu) * rs * g[i] + bt[i];
}

__device__ __forceinline__ void ln6p(const v2f* x, const float* g,
                                     const float* bt, v2f* o) {
    v2f s2 = x[0] + x[1] + x[2];
    float mu = (s2.x + s2.y) * (1.0f / 6.0f);
    v2f d0 = x[0] - mu, d1 = x[1] - mu, d2 = x[2] - mu;
    v2f vv = d0 * d0 + d1 * d1 + d2 * d2;
    float var = (vv.x + vv.y) * (1.0f / 6.0f);
    float rs = __builtin_amdgcn_rsqf(var + 1e-5f);
    const v2f* g2 = (const v2f*)g;
    const v2f* b2 = (const v2f*)bt;
    o[0] = d0 * rs * g2[0] + b2[0];
    o[1] = d1 * rs * g2[1] + b2[1];
    o[2] = d2 * rs * g2[2] + b2[2];
}

// packed gelu: erf via A&S 7.1.26 (|eps| <= 1.5e-7) — absmax proven in r2
__device__ __forceinline__ v2f gelu2(v2f s) {
    const float pc = 0.3275911f;
    const float a1 = 0.254829592f, a2 = -0.284496736f, a3 = 1.421413741f,
                a4 = -1.453152027f, a5 = 1.061405429f;
    v2f ax; ax.x = fabsf(s.x); ax.y = fabsf(s.y);
    v2f xe = ax * 0.70710678118654752f;
    v2f dn = xe * pc + 1.0f;
    v2f t;  t.x = __builtin_amdgcn_rcpf(dn.x); t.y = __builtin_amdgcn_rcpf(dn.y);
    v2f poly = ((((a5 * t + a4) * t + a3) * t + a2) * t + a1) * t;
    v2f ea = xe * xe * -1.4426950408889634f;
    v2f ee; ee.x = __builtin_amdgcn_exp2f(ea.x); ee.y = __builtin_amdgcn_exp2f(ea.y);
    v2f er = 1.0f - poly * ee;
    v2f es; es.x = copysignf(er.x, s.x); es.y = copysignf(er.y, s.y);
    return 0.5f * s * (1.0f + es);
}

__device__ __forceinline__ int nib5(unsigned k0, unsigned k1, unsigned k2,
                                    unsigned k3, unsigned k4, int pos) {
    unsigned a = (pos < 8)  ? k0 : k1;
    unsigned b = (pos < 24) ? k2 : k3;
    unsigned w = (pos < 16) ? a : b;
    w = (pos < 32) ? w : k4;
    return (int)((w >> ((pos & 7) * 4)) & 15u);
}

__device__ __forceinline__ void epilogue_row(
    v2f dn, v2f a0, v2f a1, v2f a2, int tk, int t,
    const float* __restrict__ tok_emb, const float* __restrict__ pos_enc,
    const float* __restrict__ wo,
    const float* __restrict__ ln2_g, const float* __restrict__ ln2_b,
    const float* __restrict__ w1, const float* __restrict__ b1,
    const float* __restrict__ w2, const float* __restrict__ b2,
    const float* __restrict__ lnf_g, const float* __restrict__ lnf_b,
    const float* __restrict__ w_head, float* __restrict__ orow)
{
    v2f inv;
    inv.x = __builtin_amdgcn_rcpf(dn.x);
    inv.y = __builtin_amdgcn_rcpf(dn.y);
    v2f aox = a0 * inv, aoy = a1 * inv, aoz = a2 * inv;
    float ao[6] = {aox.x, aoy.x, aoz.x, aox.y, aoy.y, aoz.y};

    float x[6];
#pragma unroll
    for (int i = 0; i < 3; ++i) x[i] = tok_emb[tk * 3 + i];
#pragma unroll
    for (int i = 0; i < 3; ++i) x[3 + i] = pos_enc[t * 3 + i];

    const v2f* wo2 = (const v2f*)wo;
    v2f X2[3] = { {x[0], x[1]}, {x[2], x[3]}, {x[4], x[5]} };
#pragma unroll
    for (int i = 0; i < 6; ++i) {
        X2[0] += ao[i] * wo2[i * 3 + 0];
        X2[1] += ao[i] * wo2[i * 3 + 1];
        X2[2] += ao[i] * wo2[i * 3 + 2];
    }

    v2f H[3];
    ln6p(X2, ln2_g, ln2_b, H);
    float h[6] = {H[0].x, H[0].y, H[1].x, H[1].y, H[2].x, H[2].y};
    const v2f* w1v = (const v2f*)w1;
    const v2f* b1v = (const v2f*)b1;
    v2f F[3] = { b1v[0], b1v[1], b1v[2] };
#pragma unroll
    for (int i = 0; i < 6; ++i) {
        F[0] += h[i] * w1v[i * 3 + 0];
        F[1] += h[i] * w1v[i * 3 + 1];
        F[2] += h[i] * w1v[i * 3 + 2];
    }
    F[0] = gelu2(F[0]); F[1] = gelu2(F[1]); F[2] = gelu2(F[2]);
    float f[6] = {F[0].x, F[0].y, F[1].x, F[1].y, F[2].x, F[2].y};
    const v2f* w2v = (const v2f*)w2;
    const v2f* b2v = (const v2f*)b2;
    v2f X3[3] = { X2[0] + b2v[0], X2[1] + b2v[1], X2[2] + b2v[2] };
#pragma unroll
    for (int i = 0; i < 6; ++i) {
        X3[0] += f[i] * w2v[i * 3 + 0];
        X3[1] += f[i] * w2v[i * 3 + 1];
        X3[2] += f[i] * w2v[i * 3 + 2];
    }

    v2f XO[3];
    ln6p(X3, lnf_g, lnf_b, XO);
    float xo[6] = {XO[0].x, XO[0].y, XO[1].x, XO[1].y, XO[2].x, XO[2].y};
    const v2f* whv = (const v2f*)w_head;
    v2f O[7] = {{0,0},{0,0},{0,0},{0,0},{0,0},{0,0},{0,0}};
#pragma unroll
    for (int i = 0; i < 6; ++i) {
#pragma unroll
        for (int j = 0; j < 7; ++j) O[j] += xo[i] * whv[i * 7 + j];
    }
    v2f* op = (v2f*)orow;
#pragma unroll
    for (int j = 0; j < 7; ++j) op[j] = O[j];
}

__global__ __launch_bounds__(BLK_THREADS, 8) void fused_tf_kernel(
    const int* __restrict__ idx,
    const float* __restrict__ tok_emb,
    const float* __restrict__ pos_enc,
    const float* __restrict__ wq,
    const float* __restrict__ wk,
    const float* __restrict__ wv,
    const float* __restrict__ wo,
    const float* __restrict__ ln1_g, const float* __restrict__ ln1_b,
    const float* __restrict__ ln2_g, const float* __restrict__ ln2_b,
    const float* __restrict__ w1,   const float* __restrict__ b1,
    const float* __restrict__ w2,   const float* __restrict__ b2,
    const float* __restrict__ lnf_g, const float* __restrict__ lnf_b,
    const float* __restrict__ w_head,
    float* __restrict__ out)
{
    // entry (80 B): [0:11] kv head-interleaved pairs, [12:17] q pairs
    // (pre-scaled by 1/sqrt(3)*log2e), [18:19] pad. stride 20 banks ->
    // only tk/tk+8 alias (2-way = free), 16-B aligned.
    __shared__ __align__(16) float kvtab[NSTATE * ESTRIDE];   // 38.1 KB
    __shared__ unsigned pk_lds[SEQS_PER_BLK * 5];             // 1.3 KB

    const int tid = threadIdx.x;

    // ---- build (t,tok) -> (k,v,q) table (proven path, now amortized 2x) ----
    if (tid < NSTATE) {
        const int e = tid;
        const int tt = e / VOCAB;
        const int v = e - tt * VOCAB;
        float x0[6];
#pragma unroll
        for (int i = 0; i < 3; ++i) x0[i] = tok_emb[v * 3 + i];
#pragma unroll
        for (int i = 0; i < 3; ++i) x0[3 + i] = pos_enc[tt * 3 + i];
        float xl[6];
        layernorm6(x0, ln1_g, ln1_b, xl);
        float kc[6], vc[6], qc[6];
        const float qs = 0.57735026918962576f * 1.4426950408889634f;
#pragma unroll
        for (int j = 0; j < 6; ++j) {
            kc[j] = xl[3] * wk[j] + xl[4] * wk[6 + j] + xl[5] * wk[12 + j];
            vc[j] = xl[0] * wv[j] + xl[1] * wv[6 + j] + xl[2] * wv[12 + j];
            qc[j] = (xl[3] * wq[j] + xl[4] * wq[6 + j] + xl[5] * wq[12 + j]) * qs;
        }
        float* dst = &kvtab[e * ESTRIDE];
        ((float4*)dst)[0] = make_float4(kc[0], kc[3], kc[1], kc[4]);
        ((float4*)dst)[1] = make_float4(kc[2], kc[5], vc[0], vc[3]);
        ((float4*)dst)[2] = make_float4(vc[1], vc[4], vc[2], vc[5]);
        ((float4*)dst)[3] = make_float4(qc[0], qc[3], qc[1], qc[4]);
        ((v2f*)dst)[8]    = v2f{qc[2], qc[5]};
    }
    // ---- pack tokens: 4 bits each, 8 per word, 5 words per sequence ----
    if (tid < SEQS_PER_BLK * 5) {
        const int sq = tid / 5;
        const int w  = tid - sq * 5;
        const int* p = idx + (size_t)blockIdx.x * (SEQS_PER_BLK * T_SEQ)
                       + sq * T_SEQ + w * 8;
        const int n = (w == 4) ? 2 : 8;
        unsigned pk = 0;
        for (int j = 0; j < n; ++j) pk |= ((unsigned)p[j]) << (4 * j);
        pk_lds[tid] = pk;
    }
    __syncthreads();

    // wave = t-row(s); lane = seq. All 64 lanes of a wave share t ->
    // causal bounds are wave-uniform scalar branches, no lane divergence.
    const int seq = tid & 63;
    const int wv_id = tid >> 6;        // 0..15, wave-uniform
    const long long bseq = (long long)blockIdx.x * SEQS_PER_BLK + seq;

    // balanced row assignment: cost(t) = t+1.
    //  w<14:  {33-w, 2+w}        cost 37
    //  w=14:  {19, 16, 1}        cost 39
    //  w=15:  {18, 17, 0}        cost 38     -> max/avg = 39/37.2 = 95%
    int r0, r1, r2;
    if (wv_id < 14)       { r0 = 33 - wv_id; r1 = 2 + wv_id; r2 = -1; }
    else if (wv_id == 14) { r0 = 19;         r1 = 16;        r2 = 1;  }
    else                  { r0 = 18;         r1 = 17;        r2 = 0;  }

    const unsigned* pkr = &pk_lds[seq * 5];
    const unsigned pk0 = pkr[0], pk1 = pkr[1], pk2 = pkr[2],
                   pk3 = pkr[3], pk4 = pkr[4];

    const char* kvb = (const char*)kvtab;
    float* outbase = out + (size_t)bseq * T_SEQ * 14;

    // static word/shift selection: s_ is a literal in every expansion
#define PKW(s_) ((s_) < 8 ? pk0 : (s_) < 16 ? pk1 : (s_) < 24 ? pk2 : \
                 (s_) < 32 ? pk3 : pk4)
#define TKN(s_) ((int)((PKW(s_) >> (((s_) & 7) * 4)) & 15u))
#define LOADS(s_, EA, EB, EC) {                                               \
    const char* ep_ = kvb + (s_) * SROW_B + TKN(s_) * ENT_B;                  \
    EA = *(const float4*)(ep_);                                               \
    EB = *(const float4*)(ep_ + 16);                                          \
    EC = *(const float4*)(ep_ + 32); }

#define KMATH(s_, EA, EB, EC, MASKED) {                                       \
    v2f sc_ = qx * v2f{EA.x, EA.y} + qy * v2f{EA.z, EA.w}                     \
            + qz * v2f{EB.x, EB.y};                                           \
    v2f pp_;                                                                  \
    pp_.x = __builtin_amdgcn_exp2f(sc_.x);                                    \
    pp_.y = __builtin_amdgcn_exp2f(sc_.y);                                    \
    if (MASKED) {                                                             \
        const bool ok_ = ((s_) <= t);                                         \
        pp_.x = ok_ ? pp_.x : 0.0f;                                           \
        pp_.y = ok_ ? pp_.y : 0.0f;                                           \
    }                                                                         \
    den += pp_;                                                               \
    A0 += pp_ * v2f{EB.z, EB.w};                                              \
    A1 += pp_ * v2f{EC.x, EC.y};                                              \
    A2 += pp_ * v2f{EC.z, EC.w}; }

#define SLOT2(sA, sB, MASKED) {                                               \
    float4 ea0, eb0, ec0, ea1, eb1, ec1;                                      \
    LOADS(sA, ea0, eb0, ec0)                                                  \
    LOADS(sB, ea1, eb1, ec1)                                                  \
    KMATH(sA, ea0, eb0, ec0, MASKED)                                          \
    KMATH(sB, ea1, eb1, ec1, MASKED) }

#define GROUP8(g_)                                                            \
    if (t >= (g_) * 8 + 7) {            /* straight-line, no masking */       \
        SLOT2((g_) * 8 + 0, (g_) * 8 + 1, 0)                                  \
        SLOT2((g_) * 8 + 2, (g_) * 8 + 3, 0)                                  \
        SLOT2((g_) * 8 + 4, (g_) * 8 + 5, 0)                                  \
        SLOT2((g_) * 8 + 6, (g_) * 8 + 7, 0)                                  \
    } else if (t >= (g_) * 8) {         /* boundary: uniform 2-slot gating */ \
        SLOT2((g_) * 8 + 0, (g_) * 8 + 1, 1)                                  \
        if (t >= (g_) * 8 + 2) { SLOT2((g_) * 8 + 2, (g_) * 8 + 3, 1) }       \
        if (t >= (g_) * 8 + 4) { SLOT2((g_) * 8 + 4, (g_) * 8 + 5, 1) }       \
        if (t >= (g_) * 8 + 6) { SLOT2((g_) * 8 + 6, (g_) * 8 + 7, 1) }       \
    }

    // row loop: trip 2-3, wave-uniform; skeleton emitted ONCE (unroll 1)
#pragma unroll 1
    for (int ri = 0; ri < 3; ++ri) {
        const int t = (ri == 0) ? r0 : ((ri == 1) ? r1 : r2);
        if (t < 0) break;               // only r2 can be -1; uniform

        const int mytok = nib5(pk0, pk1, pk2, pk3, pk4, t);

        v2f qx, qy, qz;
        {
            const char* qp = kvb + (t * VOCAB + mytok) * ENT_B + 48;
            const float4 qa = *(const float4*)qp;
            qx = v2f{qa.x, qa.y}; qy = v2f{qa.z, qa.w};
            qz = *(const v2f*)(qp + 16);
        }

        v2f den = {0, 0}, A0 = {0, 0}, A1 = {0, 0}, A2 = {0, 0};

        GROUP8(0)
        GROUP8(1)
        GROUP8(2)
        GROUP8(3)
        if (t >= 32) { SLOT2(32, 33, 1) }

        epilogue_row(den, A0, A1, A2, mytok, t, tok_emb, pos_enc, wo,
                     ln2_g, ln2_b, w1, b1, w2, b2, lnf_g, lnf_b, w_head,
                     outbase + (size_t)t * 14);
    }

#undef GROUP8
#undef SLOT2
#undef KMATH
#undef LOADS
#undef TKN
#undef PKW
}

extern "C" void kernel_launch(void* const* d_in, const int* in_sizes, int n_in,
                              void* d_out, int out_size, void* d_ws, size_t ws_size,
                              hipStream_t stream) {
    const int*   idx     = (const int*)d_in[0];
    const float* tok_emb = (const float*)d_in[1];
    const float* pos_enc = (const float*)d_in[2];
    const float* wq      = (const float*)d_in[3];
    const float* wk      = (const float*)d_in[4];
    const float* wv      = (const float*)d_in[5];
    const float* wo      = (const float*)d_in[6];
    const float* ln1_g   = (const float*)d_in[7];
    const float* ln1_b   = (const float*)d_in[8];
    const float* ln2_g   = (const float*)d_in[9];
    const float* ln2_b   = (const float*)d_in[10];
    const float* w1      = (const float*)d_in[11];
    const float* b1      = (const float*)d_in[12];
    const float* w2      = (const float*)d_in[13];
    const float* b2      = (const float*)d_in[14];
    const float* lnf_g   = (const float*)d_in[15];
    const float* lnf_b   = (const float*)d_in[16];
    const float* w_head  = (const float*)d_in[17];
    float* out = (float*)d_out;

    hipLaunchKernelGGL(fused_tf_kernel, dim3(NBLK), dim3(BLK_THREADS), 0, stream,
                       idx, tok_emb, pos_enc, wq, wk, wv, wo,
                       ln1_g, ln1_b, ln2_g, ln2_b, w1, b1, w2, b2,
                       lnf_g, lnf_b, w_head, out);
}